// Round 1
// baseline (33.332 us; speedup 1.0000x reference)
//
#include <hip/hip_runtime.h>
#include <math.h>

#define WID 640
#define HEI 480
#define SEEDS 8192
#define NBOX 512
#define NCLS 10
#define NFEAT 18

__global__ __launch_bounds__(256) void votefusion_kernel(
    const float* __restrict__ img,     // B,3,H,W
    const float* __restrict__ bb,      // B,N,6  (l,t,r,b,conf,cls)
    const float* __restrict__ seeds,   // B,S,3
    const float* __restrict__ Rt,      // B,3,3
    const float* __restrict__ Km,      // B,3,3
    float* __restrict__ out)           // B,18,S
{
    const int b = blockIdx.y;
    const int s = blockIdx.x * 256 + threadIdx.x;

    __shared__ float2 s_mid[NBOX];     // (midx, midy)
    __shared__ float4 s_ltrb[NBOX];    // (l, t, r, b)

    const float* bbB = bb + (size_t)b * NBOX * 6;
    for (int j = threadIdx.x; j < NBOX; j += 256) {
        float l  = bbB[j * 6 + 0];
        float t  = bbB[j * 6 + 1];
        float r  = bbB[j * 6 + 2];
        float bo = bbB[j * 6 + 3];
        s_mid[j]  = make_float2((l + r) * 0.5f, (t + bo) * 0.5f);
        s_ltrb[j] = make_float4(l, t, r, bo);
    }
    __syncthreads();

    // Per-sample matrices (wave-uniform)
    const float* R  = Rt + (size_t)b * 9;
    const float* Ko = Km + (size_t)b * 9;
    const float R00 = R[0], R01 = R[1], R02 = R[2];
    const float R10 = R[3], R11 = R[4], R12 = R[5];
    const float R20 = R[6], R21 = R[7], R22 = R[8];
    const float K00 = Ko[0], K01 = Ko[1], K02 = Ko[2];
    const float K10 = Ko[3], K11 = Ko[4], K12 = Ko[5];
    const float K20 = Ko[6], K21 = Ko[7], K22 = Ko[8];

    // Seed -> cam -> 2D projection
    const float* sp = seeds + ((size_t)b * SEEDS + s) * 3;
    const float s0 = sp[0], s1 = sp[1], s2 = sp[2];
    // q = seeds @ Rt.T  (q_i = sum_j Rt[i][j] * s_j)
    const float q0 = R00 * s0 + R01 * s1 + R02 * s2;
    const float q1 = R10 * s0 + R11 * s1 + R12 * s2;
    const float q2 = R20 * s0 + R21 * s1 + R22 * s2;
    // cam = (q0, -q2, q1)
    const float cam0 = q0, cam1 = -q2, cam2 = q1;
    // uv = cam @ K.T
    const float uv0 = K00 * cam0 + K01 * cam1 + K02 * cam2;
    const float uv1 = K10 * cam0 + K11 * cam1 + K12 * cam2;
    const float uv2 = K20 * cam0 + K21 * cam1 + K22 * cam2;
    const float sxe = uv0 / uv2;   // unclipped seed_2d.x
    const float sye = uv1 / uv2;   // unclipped seed_2d.y

    // Scan boxes: argmin of center distance^2 (first-min tie-break) + any-in-box
    float best = 3.0e38f;
    int   bi   = 0;
    int   any  = 0;
    #pragma unroll 4
    for (int j = 0; j < NBOX; ++j) {
        const float2 m  = s_mid[j];
        const float  du = __fsub_rn(m.x, sxe);
        const float  dv = __fsub_rn(m.y, sye);
        const float  d2 = __fadd_rn(__fmul_rn(du, du), __fmul_rn(dv, dv));
        if (d2 < best) { best = d2; bi = j; }
        const float4 bx = s_ltrb[j];
        any |= (sxe > bx.x) & (sxe < bx.z) & (sye > bx.y) & (sye < bx.w);
    }

    float outv[NFEAT];
    if (!any) {
        #pragma unroll
        for (int f = 0; f < NFEAT; ++f) outv[f] = 0.0f;
    } else {
        // sem one-hot * conf at assigned box
        const float conf = bbB[bi * 6 + 4];
        const int   cls  = (int)bbB[bi * 6 + 5];
        #pragma unroll
        for (int f = 0; f < NCLS; ++f) outv[f] = (f == cls) ? conf : 0.0f;

        // txt: gather image at clipped/floored seed 2D position
        const float sx = fminf(fmaxf(sxe, 0.0f), (float)(WID - 1));
        const float sy = fminf(fmaxf(sye, 0.0f), (float)(HEI - 1));
        const int ix = (int)floorf(sx);
        const int iy = (int)floorf(sy);
        const int pidx = iy * WID + ix;
        const float* imgB = img + (size_t)b * 3 * HEI * WID;
        outv[10] = (imgB[0 * HEI * WID + pidx] + 103.53f  - 128.0f) * (1.0f / 128.0f);
        outv[11] = (imgB[1 * HEI * WID + pidx] + 116.28f  - 128.0f) * (1.0f / 128.0f);
        outv[12] = (imgB[2 * HEI * WID + pidx] + 123.675f - 128.0f) * (1.0f / 128.0f);

        // geo cue at assigned box
        const float2 mb = s_mid[bi];
        const float du = mb.x - sxe;
        const float dv = mb.y - sye;
        const float x3 = cam0, y3 = cam1, z3 = cam2;
        const float geo0 = du * (z3 / K00);   // f_u = K[0][0]
        const float geo1 = dv * (z3 / K11);   // f_v = K[1][1]

        // geo_xy = (geo0, 0, -geo1) @ Rt   (result_j = sum_i q_i * Rt[i][j])
        const float gxy0 = geo0 * R00 - geo1 * R20;
        const float gxy1 = geo0 * R01 - geo1 * R21;
        const float gxy2 = geo0 * R02 - geo1 * R22;
        const float ratio = s1 / (s1 + gxy1);       // seed_depth = seeds[:,1]
        const float gx = gxy0 * ratio;
        const float gz = gxy2 * ratio;

        // geo_vec = (geo0+x3, z3, -(geo1+y3)) @ Rt, normalized
        const float a0 = geo0 + x3;
        const float a1 = z3;
        const float a2 = -(geo1 + y3);
        float gv0 = a0 * R00 + a1 * R10 + a2 * R20;
        float gv1 = a0 * R01 + a1 * R11 + a2 * R21;
        float gv2 = a0 * R02 + a1 * R12 + a2 * R22;
        const float nrm = sqrtf(gv0 * gv0 + gv1 * gv1 + gv2 * gv2);
        gv0 /= nrm; gv1 /= nrm; gv2 /= nrm;

        outv[13] = gx;
        outv[14] = gz;
        outv[15] = gv0;
        outv[16] = gv1;
        outv[17] = gv2;
    }

    // out[b][f][s]
    const size_t base = (size_t)b * NFEAT * SEEDS + s;
    #pragma unroll
    for (int f = 0; f < NFEAT; ++f) out[base + (size_t)f * SEEDS] = outv[f];
}

extern "C" void kernel_launch(void* const* d_in, const int* in_sizes, int n_in,
                              void* d_out, int out_size, void* d_ws, size_t ws_size,
                              hipStream_t stream) {
    const float* img   = (const float*)d_in[0];
    const float* bb    = (const float*)d_in[1];
    const float* seeds = (const float*)d_in[2];
    const float* Rt    = (const float*)d_in[3];
    const float* K     = (const float*)d_in[4];
    float* out = (float*)d_out;

    const int B = in_sizes[1] / (NBOX * 6);
    dim3 grid(SEEDS / 256, B);
    votefusion_kernel<<<grid, 256, 0, stream>>>(img, bb, seeds, Rt, K, out);
}

// Round 2
// 13.469 us; speedup vs baseline: 2.4747x; 2.4747x over previous
//
#include <hip/hip_runtime.h>
#include <math.h>

#define WID 640
#define HEI 480
#define SEEDS 8192
#define NBOX 512
#define NCLS 10
#define NFEAT 18
#define TPS 16              // threads per seed
#define SPB 16              // seeds per block (256 / TPS)

__global__ __launch_bounds__(256) void votefusion_kernel(
    const float* __restrict__ img,     // B,3,H,W
    const float* __restrict__ bb,      // B,N,6  (l,t,r,b,conf,cls)
    const float* __restrict__ seeds,   // B,S,3
    const float* __restrict__ Rt,      // B,3,3
    const float* __restrict__ Km,      // B,3,3
    float* __restrict__ out)           // B,18,S
{
    const int b   = blockIdx.y;
    const int tid = threadIdx.x;
    const int grp = tid / TPS;          // seed slot in block
    const int t   = tid % TPS;          // lane within seed group
    const int s   = blockIdx.x * SPB + grp;

    __shared__ float2 s_mid[NBOX];      // (midx, midy)
    __shared__ float4 s_ltrb[NBOX];     // (l, t, r, b)
    __shared__ float2 s_cc[NBOX];       // (conf, cls)

    const float* bbB = bb + (size_t)b * NBOX * 6;
    for (int j = tid; j < NBOX; j += 256) {
        float l  = bbB[j * 6 + 0];
        float tt = bbB[j * 6 + 1];
        float r  = bbB[j * 6 + 2];
        float bo = bbB[j * 6 + 3];
        s_mid[j]  = make_float2((l + r) * 0.5f, (tt + bo) * 0.5f);
        s_ltrb[j] = make_float4(l, tt, r, bo);
        s_cc[j]   = make_float2(bbB[j * 6 + 4], bbB[j * 6 + 5]);
    }
    __syncthreads();

    // Per-sample matrices (wave-uniform)
    const float* R  = Rt + (size_t)b * 9;
    const float* Ko = Km + (size_t)b * 9;
    const float R00 = R[0], R01 = R[1], R02 = R[2];
    const float R10 = R[3], R11 = R[4], R12 = R[5];
    const float R20 = R[6], R21 = R[7], R22 = R[8];
    const float K00 = Ko[0], K01 = Ko[1], K02 = Ko[2];
    const float K10 = Ko[3], K11 = Ko[4], K12 = Ko[5];
    const float K20 = Ko[6], K21 = Ko[7], K22 = Ko[8];

    // Seed -> cam -> 2D projection (redundant across the 16 lanes of a group)
    const float* sp = seeds + ((size_t)b * SEEDS + s) * 3;
    const float s0 = sp[0], s1 = sp[1], s2 = sp[2];
    const float q0 = R00 * s0 + R01 * s1 + R02 * s2;
    const float q1 = R10 * s0 + R11 * s1 + R12 * s2;
    const float q2 = R20 * s0 + R21 * s1 + R22 * s2;
    const float cam0 = q0, cam1 = -q2, cam2 = q1;
    const float uv0 = K00 * cam0 + K01 * cam1 + K02 * cam2;
    const float uv1 = K10 * cam0 + K11 * cam1 + K12 * cam2;
    const float uv2 = K20 * cam0 + K21 * cam1 + K22 * cam2;
    const float sxe = uv0 / uv2;
    const float sye = uv1 / uv2;

    // Scan my 32 boxes (interleaved): packed argmin key + any-in-box
    unsigned long long key = 0xFFFFFFFFFFFFFFFFull;
    int any = 0;
    #pragma unroll 4
    for (int i = 0; i < NBOX / TPS; ++i) {
        const int j = i * TPS + t;
        const float2 m  = s_mid[j];
        const float  du = __fsub_rn(m.x, sxe);
        const float  dv = __fsub_rn(m.y, sye);
        const float  d2 = __fadd_rn(__fmul_rn(du, du), __fmul_rn(dv, dv));
        const unsigned long long k =
            ((unsigned long long)__float_as_uint(d2) << 32) | (unsigned)j;
        key = (k < key) ? k : key;
        const float4 bx = s_ltrb[j];
        any |= (sxe > bx.x) & (sxe < bx.z) & (sye > bx.y) & (sye < bx.w);
    }

    // Butterfly reduce across the 16-lane group
    #pragma unroll
    for (int m = 1; m < TPS; m <<= 1) {
        const unsigned long long ok = __shfl_xor(key, m);
        key = (ok < key) ? ok : key;
        any |= __shfl_xor(any, m);
    }

    if (t != 0) return;

    const size_t base = (size_t)b * NFEAT * SEEDS + s;
    if (!any) {
        #pragma unroll
        for (int f = 0; f < NFEAT; ++f) out[base + (size_t)f * SEEDS] = 0.0f;
        return;
    }

    const int bi = (int)(unsigned)(key & 0xFFFFFFFFull);

    float outv[NFEAT];
    // sem one-hot * conf at assigned box
    const float2 cc = s_cc[bi];
    const float conf = cc.x;
    const int   cls  = (int)cc.y;
    #pragma unroll
    for (int f = 0; f < NCLS; ++f) outv[f] = (f == cls) ? conf : 0.0f;

    // txt: gather image at clipped/floored seed 2D position
    const float sx = fminf(fmaxf(sxe, 0.0f), (float)(WID - 1));
    const float sy = fminf(fmaxf(sye, 0.0f), (float)(HEI - 1));
    const int ix = (int)floorf(sx);
    const int iy = (int)floorf(sy);
    const int pidx = iy * WID + ix;
    const float* imgB = img + (size_t)b * 3 * HEI * WID;
    outv[10] = (imgB[0 * HEI * WID + pidx] + 103.53f  - 128.0f) * (1.0f / 128.0f);
    outv[11] = (imgB[1 * HEI * WID + pidx] + 116.28f  - 128.0f) * (1.0f / 128.0f);
    outv[12] = (imgB[2 * HEI * WID + pidx] + 123.675f - 128.0f) * (1.0f / 128.0f);

    // geo cue at assigned box
    const float2 mb = s_mid[bi];
    const float du = mb.x - sxe;
    const float dv = mb.y - sye;
    const float x3 = cam0, y3 = cam1, z3 = cam2;
    const float geo0 = du * (z3 / K00);
    const float geo1 = dv * (z3 / K11);

    // geo_xy = (geo0, 0, -geo1) @ Rt
    const float gxy0 = geo0 * R00 - geo1 * R20;
    const float gxy1 = geo0 * R01 - geo1 * R21;
    const float gxy2 = geo0 * R02 - geo1 * R22;
    const float ratio = s1 / (s1 + gxy1);
    outv[13] = gxy0 * ratio;
    outv[14] = gxy2 * ratio;

    // geo_vec = (geo0+x3, z3, -(geo1+y3)) @ Rt, normalized
    const float a0 = geo0 + x3;
    const float a1 = z3;
    const float a2 = -(geo1 + y3);
    float gv0 = a0 * R00 + a1 * R10 + a2 * R20;
    float gv1 = a0 * R01 + a1 * R11 + a2 * R21;
    float gv2 = a0 * R02 + a1 * R12 + a2 * R22;
    const float nrm = sqrtf(gv0 * gv0 + gv1 * gv1 + gv2 * gv2);
    outv[15] = gv0 / nrm;
    outv[16] = gv1 / nrm;
    outv[17] = gv2 / nrm;

    #pragma unroll
    for (int f = 0; f < NFEAT; ++f) out[base + (size_t)f * SEEDS] = outv[f];
}

extern "C" void kernel_launch(void* const* d_in, const int* in_sizes, int n_in,
                              void* d_out, int out_size, void* d_ws, size_t ws_size,
                              hipStream_t stream) {
    const float* img   = (const float*)d_in[0];
    const float* bb    = (const float*)d_in[1];
    const float* seeds = (const float*)d_in[2];
    const float* Rt    = (const float*)d_in[3];
    const float* K     = (const float*)d_in[4];
    float* out = (float*)d_out;

    const int B = in_sizes[1] / (NBOX * 6);
    dim3 grid(SEEDS / SPB, B);
    votefusion_kernel<<<grid, 256, 0, stream>>>(img, bb, seeds, Rt, K, out);
}